// Round 21
// baseline (93.450 us; speedup 1.0000x reference)
//
#include <hip/hip_runtime.h>

#define KLEN 1024
#define HOP 512
#define NW 511
#define NB 4
#define NC 16
#define NBINS 513
#define NSAMP 262144
#define MAPN (NC * KLEN)

// ws layout (bytes):
//   map  float4[MAPN]  @ 0        {lo_bits, frac, jac, 0}
//   tw   float2[512]   @ 262144   {cos, -sin}
//   hann float[1024]   @ 266240
#define WS_TW   262144
#define WS_HANN 266240

#define PAD2(i) ((i) + ((i) >> 4))   // skew pad in float2 units

__global__ __launch_bounds__(256) void warpmap_kernel(
    const float* __restrict__ dlnf,
    float4* __restrict__ map, float2* __restrict__ g_tw, float* __restrict__ g_hann)
{
    const int c = blockIdx.x;
    const double TWO_PI = 6.283185307179586476925287;
    const double beta = 2.0 * (double)dlnf[c];
    const bool small = fabs(beta) < 1e-8;
    const double bs = small ? 1e-8 : beta;
    const double e2b = exp(2.0 * bs);
    const double t_mid = small ? 0.0 : (log(1.0 + 0.5 * (e2b - 1.0)) / bs - 1.0);

    for (int j = threadIdx.x; j < KLEN; j += 256) {
        double tau = 2.0 * (double)j / 1024.0 - 1.0;
        double ts, jac;
        if (small) { ts = tau; jac = 1.0; }
        else {
            ts = log(1.0 + (tau + 1.0) * 0.5 * (e2b - 1.0)) / bs - 1.0;
            jac = exp(-bs * (ts - t_mid));
        }
        double idxf = 512.0 * (ts + 1.0);
        int lo = (int)idxf;
        lo = lo < 0 ? 0 : (lo > 1022 ? 1022 : lo);
        map[c * KLEN + j] = make_float4(__int_as_float(lo),
                                        (float)(idxf - (double)lo),
                                        (float)jac, 0.0f);
    }

    if (c == 0) {
        for (int t = threadIdx.x; t < 512; t += 256) {
            double ang = TWO_PI * (double)t / 1024.0;
            g_tw[t] = make_float2((float)cos(ang), (float)(-sin(ang)));
        }
        for (int k = threadIdx.x; k < KLEN; k += 256)
            g_hann[k] = (float)(0.5 * (1.0 - cos(TWO_PI * (double)k / 1024.0)));
    }
}

__global__ __launch_bounds__(256) void dechirp_fftz_kernel(
    const float* __restrict__ x,
    const float4* __restrict__ map,
    const float2* __restrict__ g_tw,
    const float* __restrict__ g_hann,
    float* __restrict__ out)
{
    __shared__ float wd[KLEN];
    __shared__ float2 z[PAD2(KLEN - 1) + 1];
    __shared__ float2 tw[512];

    const int tid = threadIdx.x;
    const int blin = blockIdx.x;            // ((b*NW + w)*8 + q)
    const int q = blin & 7;
    const int w = (blin >> 3) % NW;
    const int b = blin / (8 * NW);
    const int c0 = 2 * q, c1 = 2 * q + 1;

    for (int t = tid; t < 512; t += 256) tw[t] = g_tw[t];
    const float* xrow = x + (size_t)b * NSAMP + (size_t)w * HOP;
    for (int k = tid; k < KLEN; k += 256)
        wd[k] = xrow[k] * g_hann[k];
    __syncthreads();

    // Resample both chirps; pack z = f + i*g at bit-reversed (padded) slots
    const float4* m0 = map + c0 * KLEN;
    const float4* m1 = map + c1 * KLEN;
    for (int j = tid; j < KLEN; j += 256) {
        float4 a = m0[j];
        int   a0 = __float_as_int(a.x);
        float vf = (wd[a0] * (1.0f - a.y) + wd[a0 + 1] * a.y) * a.z;
        float4 bb = m1[j];
        int   a1 = __float_as_int(bb.x);
        float vg = (wd[a1] * (1.0f - bb.y) + wd[a1 + 1] * bb.y) * bb.z;
        int r = (int)(__brev((unsigned)j) >> 22);
        z[PAD2(r)] = make_float2(vf, vg);
    }
    __syncthreads();

    // 5 fused double-stages (radix-4 groups), float2 LDS
    #pragma unroll
    for (int s = 0; s <= 8; s += 2) {
        const int h = 1 << s;
        const int j = tid & (h - 1);
        const int base = ((tid >> s) << (s + 2)) + j;
        const int i0 = PAD2(base), i1 = PAD2(base + h);
        const int i2 = PAD2(base + 2 * h), i3 = PAD2(base + 3 * h);

        float2 z0 = z[i0], z1 = z[i1], z2 = z[i2], z3 = z[i3];
        float2 wA = tw[j << (9 - s)];

        float v1r = z1.x * wA.x - z1.y * wA.y, v1i = z1.x * wA.y + z1.y * wA.x;
        float b0r = z0.x + v1r, b0i = z0.y + v1i;
        float b1r = z0.x - v1r, b1i = z0.y - v1i;
        float v3r = z3.x * wA.x - z3.y * wA.y, v3i = z3.x * wA.y + z3.y * wA.x;
        float b2r = z2.x + v3r, b2i = z2.y + v3i;
        float b3r = z2.x - v3r, b3i = z2.y - v3i;

        float2 wB0 = tw[j << (8 - s)];
        float2 wB1 = tw[(j + h) << (8 - s)];
        float v2r = b2r * wB0.x - b2i * wB0.y, v2i = b2r * wB0.y + b2i * wB0.x;
        float v3br = b3r * wB1.x - b3i * wB1.y, v3bi = b3r * wB1.y + b3i * wB1.x;

        z[i0] = make_float2(b0r + v2r,  b0i + v2i);
        z[i2] = make_float2(b0r - v2r,  b0i - v2i);
        z[i1] = make_float2(b1r + v3br, b1i + v3bi);
        z[i3] = make_float2(b1r - v3br, b1i - v3bi);
        __syncthreads();
    }

    // Unpack real parts: Re F_k = (zk.x + zr.x)/2 ; Re G_k = (zk.y + zr.y)/2
    size_t obase0 = (((size_t)b * NW + w) * NC + c0) * NBINS;
    size_t obase1 = obase0 + NBINS;
    for (int k = tid; k < NBINS; k += 256) {
        int rk = (KLEN - k) & (KLEN - 1);
        float2 zk = z[PAD2(k)], zr = z[PAD2(rk)];
        out[obase0 + k] = 0.5f * (zk.x + zr.x);
        out[obase1 + k] = 0.5f * (zk.y + zr.y);
    }
}

extern "C" void kernel_launch(void* const* d_in, const int* in_sizes, int n_in,
                              void* d_out, int out_size, void* d_ws, size_t ws_size,
                              hipStream_t stream) {
    const float* x = nullptr;
    const float* dlnf = nullptr;
    for (int i = 0; i < n_in; ++i) {
        if (in_sizes[i] == NB * NSAMP)      x = (const float*)d_in[i];
        else if (in_sizes[i] == NC)         dlnf = (const float*)d_in[i];
    }
    if (!x)    x    = (const float*)d_in[0];
    if (!dlnf) dlnf = (const float*)d_in[1];
    float* out = (float*)d_out;

    char* ws = (char*)d_ws;
    float4* map    = (float4*)ws;
    float2* g_tw   = (float2*)(ws + WS_TW);
    float*  g_hann = (float*)(ws + WS_HANN);

    warpmap_kernel<<<NC, 256, 0, stream>>>(dlnf, map, g_tw, g_hann);

    const int nblocks = NB * NW * (NC / 2);  // 16352
    dechirp_fftz_kernel<<<nblocks, 256, 0, stream>>>(x, map, g_tw, g_hann, out);
}

// Round 22
// 79.409 us; speedup vs baseline: 1.1768x; 1.1768x over previous
//
#include <hip/hip_runtime.h>

#define KLEN 1024
#define HOP 512
#define NW 511
#define NB 4
#define NC 16
#define NBINS 513
#define NSAMP 262144
#define MAPN (NC * KLEN)

// ws layout (bytes): map float4[MAPN] @0 | tw float2[512] @262144 | hann float[1024] @266240
#define WS_TW   262144
#define WS_HANN 266240

// Bank-XOR swizzle: bijective in every 32-float segment; all FFT strides <=2-way.
#define SWZ(i) (((i) & ~31) | (((i) ^ ((i) >> 5) ^ ((i) >> 10)) & 31))

__global__ __launch_bounds__(256) void warpmap_kernel(
    const float* __restrict__ dlnf,
    float4* __restrict__ map, float2* __restrict__ g_tw, float* __restrict__ g_hann)
{
    const int c = blockIdx.x;
    const double TWO_PI = 6.283185307179586476925287;
    const double beta = 2.0 * (double)dlnf[c];
    const bool small = fabs(beta) < 1e-8;
    const double bs = small ? 1e-8 : beta;
    const double e2b = exp(2.0 * bs);
    const double t_mid = small ? 0.0 : (log(1.0 + 0.5 * (e2b - 1.0)) / bs - 1.0);

    for (int j = threadIdx.x; j < KLEN; j += 256) {
        double tau = 2.0 * (double)j / 1024.0 - 1.0;
        double ts, jac;
        if (small) { ts = tau; jac = 1.0; }
        else {
            ts = log(1.0 + (tau + 1.0) * 0.5 * (e2b - 1.0)) / bs - 1.0;
            jac = exp(-bs * (ts - t_mid));
        }
        double idxf = 512.0 * (ts + 1.0);
        int lo = (int)idxf;
        lo = lo < 0 ? 0 : (lo > 1022 ? 1022 : lo);
        map[c * KLEN + j] = make_float4(__int_as_float(lo),
                                        (float)(idxf - (double)lo),
                                        (float)jac, 0.0f);
    }

    if (c == 0) {
        for (int t = threadIdx.x; t < 512; t += 256) {
            double ang = TWO_PI * (double)t / 1024.0;
            g_tw[t] = make_float2((float)cos(ang), (float)(-sin(ang)));
        }
        for (int k = threadIdx.x; k < KLEN; k += 256)
            g_hann[k] = (float)(0.5 * (1.0 - cos(TWO_PI * (double)k / 1024.0)));
    }
}

__global__ __launch_bounds__(256) void dechirp_fftw_kernel(
    const float* __restrict__ x,
    const float4* __restrict__ map,
    const float2* __restrict__ g_tw,
    const float* __restrict__ g_hann,
    float* __restrict__ out)
{
    __shared__ float wd[KLEN];
    __shared__ float2 tw[512];
    __shared__ float reA[4][KLEN], imA[4][KLEN];

    const int tid  = threadIdx.x;
    const int lane = tid & 63;
    const int wv   = tid >> 6;
    const int blin = blockIdx.x;            // (b*NW + w)*2 + half
    const int half = blin & 1;
    const int w    = (blin >> 1) % NW;
    const int b    = blin / (2 * NW);
    const int q    = half * 4 + wv;         // chirp pair handled by this wave
    const int c0 = 2 * q, c1 = 2 * q + 1;

    // Shared staging (one barrier total)
    for (int t = tid; t < 512; t += 256) tw[t] = g_tw[t];
    const float* xrow = x + (size_t)b * NSAMP + (size_t)w * HOP;
    for (int k = tid; k < KLEN; k += 256)
        wd[k] = xrow[k] * g_hann[k];
    __syncthreads();

    float* re = reA[wv];
    float* im = imA[wv];

    // Resample both chirps; scatter to bit-reversed swizzled slots (wave-private)
    const float4* m0 = map + c0 * KLEN;
    const float4* m1 = map + c1 * KLEN;
    #pragma unroll 4
    for (int t = 0; t < 16; ++t) {
        int j = lane + (t << 6);
        float4 a = m0[j];
        int   a0 = __float_as_int(a.x);
        float vf = (wd[a0] * (1.0f - a.y) + wd[a0 + 1] * a.y) * a.z;
        float4 bb = m1[j];
        int   a1 = __float_as_int(bb.x);
        float vg = (wd[a1] * (1.0f - bb.y) + wd[a1 + 1] * bb.y) * bb.z;
        int r = (int)(__brev((unsigned)j) >> 22);
        re[SWZ(r)] = vf;
        im[SWZ(r)] = vg;
    }
    __builtin_amdgcn_wave_barrier();

    // 5 fused double-stages, wave-synchronous (no __syncthreads)
    #pragma unroll
    for (int s = 0; s <= 8; s += 2) {
        const int h = 1 << s;
        #pragma unroll
        for (int g = 0; g < 4; ++g) {
            const int m = lane + (g << 6);          // group id 0..255
            const int j = m & (h - 1);
            const int base = ((m >> s) << (s + 2)) | j;
            const int i0 = SWZ(base), i1 = SWZ(base + h);
            const int i2 = SWZ(base + 2 * h), i3 = SWZ(base + 3 * h);

            float ar0 = re[i0], ai0 = im[i0];
            float ar1 = re[i1], ai1 = im[i1];
            float ar2 = re[i2], ai2 = im[i2];
            float ar3 = re[i3], ai3 = im[i3];

            float2 wA = tw[j << (9 - s)];
            float v1r = ar1 * wA.x - ai1 * wA.y, v1i = ar1 * wA.y + ai1 * wA.x;
            float b0r = ar0 + v1r, b0i = ai0 + v1i;
            float b1r = ar0 - v1r, b1i = ai0 - v1i;
            float v3r = ar3 * wA.x - ai3 * wA.y, v3i = ar3 * wA.y + ai3 * wA.x;
            float b2r = ar2 + v3r, b2i = ai2 + v3i;
            float b3r = ar2 - v3r, b3i = ai2 - v3i;

            float2 wB0 = tw[j << (8 - s)];
            float2 wB1 = tw[(j + h) << (8 - s)];
            float v2r = b2r * wB0.x - b2i * wB0.y, v2i = b2r * wB0.y + b2i * wB0.x;
            float v3br = b3r * wB1.x - b3i * wB1.y, v3bi = b3r * wB1.y + b3i * wB1.x;

            re[i0] = b0r + v2r;  im[i0] = b0i + v2i;
            re[i2] = b0r - v2r;  im[i2] = b0i - v2i;
            re[i1] = b1r + v3br; im[i1] = b1i + v3bi;
            re[i3] = b1r - v3br; im[i3] = b1i - v3bi;
        }
        __builtin_amdgcn_wave_barrier();
    }

    // Unpack real parts: Re F_k = (re[k]+re[N-k])/2 ; Re G_k = (im[k]+im[N-k])/2
    size_t obase0 = (((size_t)b * NW + w) * NC + c0) * NBINS;
    size_t obase1 = obase0 + NBINS;
    #pragma unroll
    for (int t = 0; t < 9; ++t) {
        int k = lane + (t << 6);
        if (k < NBINS) {
            int rk = (KLEN - k) & (KLEN - 1);
            float fr = 0.5f * (re[SWZ(k)] + re[SWZ(rk)]);
            float gr = 0.5f * (im[SWZ(k)] + im[SWZ(rk)]);
            out[obase0 + k] = fr;
            out[obase1 + k] = gr;
        }
    }
}

extern "C" void kernel_launch(void* const* d_in, const int* in_sizes, int n_in,
                              void* d_out, int out_size, void* d_ws, size_t ws_size,
                              hipStream_t stream) {
    const float* x = nullptr;
    const float* dlnf = nullptr;
    for (int i = 0; i < n_in; ++i) {
        if (in_sizes[i] == NB * NSAMP)      x = (const float*)d_in[i];
        else if (in_sizes[i] == NC)         dlnf = (const float*)d_in[i];
    }
    if (!x)    x    = (const float*)d_in[0];
    if (!dlnf) dlnf = (const float*)d_in[1];
    float* out = (float*)d_out;

    char* ws = (char*)d_ws;
    float4* map    = (float4*)ws;
    float2* g_tw   = (float2*)(ws + WS_TW);
    float*  g_hann = (float*)(ws + WS_HANN);

    warpmap_kernel<<<NC, 256, 0, stream>>>(dlnf, map, g_tw, g_hann);

    const int nblocks = NB * NW * 2;  // 4088 blocks, 4 waves each, 1 chirp-pair per wave
    dechirp_fftw_kernel<<<nblocks, 256, 0, stream>>>(x, map, g_tw, g_hann, out);
}

// Round 23
// 64.785 us; speedup vs baseline: 1.4425x; 1.2257x over previous
//
#include <hip/hip_runtime.h>

#define KLEN 1024
#define HOP 512
#define NW 511
#define NB 4
#define NC 16
#define NBINS 513
#define NSAMP 262144
#define MAPN (NC * KLEN)

// ws layout (bytes): map float4[MAPN] @0 | hann float[1024] @262144
#define WS_HANN 262144

// Bank-XOR swizzle: bijective in every 32-float segment; all FFT strides <=2-way.
#define SWZ(i) (((i) & ~31) | (((i) ^ ((i) >> 5) ^ ((i) >> 10)) & 31))

__global__ __launch_bounds__(256) void warpmap_kernel(
    const float* __restrict__ dlnf,
    float4* __restrict__ map, float* __restrict__ g_hann)
{
    const int c = blockIdx.x;
    const double TWO_PI = 6.283185307179586476925287;
    const double beta = 2.0 * (double)dlnf[c];
    const bool small = fabs(beta) < 1e-8;
    const double bs = small ? 1e-8 : beta;
    const double e2b = exp(2.0 * bs);
    const double t_mid = small ? 0.0 : (log(1.0 + 0.5 * (e2b - 1.0)) / bs - 1.0);

    for (int j = threadIdx.x; j < KLEN; j += 256) {
        double tau = 2.0 * (double)j / 1024.0 - 1.0;
        double ts, jac;
        if (small) { ts = tau; jac = 1.0; }
        else {
            ts = log(1.0 + (tau + 1.0) * 0.5 * (e2b - 1.0)) / bs - 1.0;
            jac = exp(-bs * (ts - t_mid));
        }
        double idxf = 512.0 * (ts + 1.0);
        int lo = (int)idxf;
        lo = lo < 0 ? 0 : (lo > 1022 ? 1022 : lo);
        map[c * KLEN + j] = make_float4(__int_as_float(lo),
                                        (float)(idxf - (double)lo),
                                        (float)jac, 0.0f);
    }

    if (c == 0) {
        for (int k = threadIdx.x; k < KLEN; k += 256)
            g_hann[k] = (float)(0.5 * (1.0 - cos(TWO_PI * (double)k / 1024.0)));
    }
}

__global__ __launch_bounds__(256) void dechirp_fftw_kernel(
    const float* __restrict__ x,
    const float4* __restrict__ map,
    const float* __restrict__ g_hann,
    float* __restrict__ out)
{
    __shared__ float wd[KLEN];
    __shared__ float reA[4][KLEN], imA[4][KLEN];

    const int tid  = threadIdx.x;
    const int lane = tid & 63;
    const int wv   = tid >> 6;
    const int blin = blockIdx.x;            // (b*NW + w)*2 + half
    const int half = blin & 1;
    const int w    = (blin >> 1) % NW;
    const int b    = blin / (2 * NW);
    const int q    = half * 4 + wv;         // chirp pair handled by this wave
    const int c0 = 2 * q, c1 = 2 * q + 1;

    // Shared staging (one barrier total)
    const float* xrow = x + (size_t)b * NSAMP + (size_t)w * HOP;
    for (int k = tid; k < KLEN; k += 256)
        wd[k] = xrow[k] * g_hann[k];
    __syncthreads();

    float* re = reA[wv];
    float* im = imA[wv];

    // Resample both chirps; scatter to bit-reversed swizzled slots (wave-private)
    const float4* m0 = map + c0 * KLEN;
    const float4* m1 = map + c1 * KLEN;
    #pragma unroll 4
    for (int t = 0; t < 16; ++t) {
        int j = lane + (t << 6);
        float4 a = m0[j];
        int   a0 = __float_as_int(a.x);
        float vf = (wd[a0] * (1.0f - a.y) + wd[a0 + 1] * a.y) * a.z;
        float4 bb = m1[j];
        int   a1 = __float_as_int(bb.x);
        float vg = (wd[a1] * (1.0f - bb.y) + wd[a1 + 1] * bb.y) * bb.z;
        int r = (int)(__brev((unsigned)j) >> 22);
        re[SWZ(r)] = vf;
        im[SWZ(r)] = vg;
    }
    __builtin_amdgcn_wave_barrier();

    // 5 fused double-stages, wave-synchronous; twiddles via sincos:
    //   wB0 = W^e (e = j*2^(8-s)),  wA = wB0^2,  wB1 = wB0 * (-i)
    #pragma unroll
    for (int s = 0; s <= 8; s += 2) {
        const int h = 1 << s;
        #pragma unroll
        for (int g = 0; g < 4; ++g) {
            const int m = lane + (g << 6);          // group id 0..255
            const int j = m & (h - 1);
            const int base = ((m >> s) << (s + 2)) | j;
            const int i0 = SWZ(base), i1 = SWZ(base + h);
            const int i2 = SWZ(base + 2 * h), i3 = SWZ(base + 3 * h);

            float ar0 = re[i0], ai0 = im[i0];
            float ar1 = re[i1], ai1 = im[i1];
            float ar2 = re[i2], ai2 = im[i2];
            float ar3 = re[i3], ai3 = im[i3];

            // twiddle: one sincos per group
            float ang = (float)(j << (8 - s)) * (-6.283185307179586f / 1024.0f);
            float sn, cs;
            __sincosf(ang, &sn, &cs);
            float wB0x = cs,              wB0y = sn;          // W^e
            float wAx  = cs * cs - sn * sn, wAy = 2.0f * cs * sn; // W^{2e}
            float wB1x = sn,              wB1y = -cs;         // W^{e+256}

            float v1r = ar1 * wAx - ai1 * wAy, v1i = ar1 * wAy + ai1 * wAx;
            float b0r = ar0 + v1r, b0i = ai0 + v1i;
            float b1r = ar0 - v1r, b1i = ai0 - v1i;
            float v3r = ar3 * wAx - ai3 * wAy, v3i = ar3 * wAy + ai3 * wAx;
            float b2r = ar2 + v3r, b2i = ai2 + v3i;
            float b3r = ar2 - v3r, b3i = ai2 - v3i;

            float v2r = b2r * wB0x - b2i * wB0y, v2i = b2r * wB0y + b2i * wB0x;
            float v3br = b3r * wB1x - b3i * wB1y, v3bi = b3r * wB1y + b3i * wB1x;

            re[i0] = b0r + v2r;  im[i0] = b0i + v2i;
            re[i2] = b0r - v2r;  im[i2] = b0i - v2i;
            re[i1] = b1r + v3br; im[i1] = b1i + v3bi;
            re[i3] = b1r - v3br; im[i3] = b1i - v3bi;
        }
        __builtin_amdgcn_wave_barrier();
    }

    // Unpack real parts: Re F_k = (re[k]+re[N-k])/2 ; Re G_k = (im[k]+im[N-k])/2
    size_t obase0 = (((size_t)b * NW + w) * NC + c0) * NBINS;
    size_t obase1 = obase0 + NBINS;
    #pragma unroll
    for (int t = 0; t < 9; ++t) {
        int k = lane + (t << 6);
        if (k < NBINS) {
            int rk = (KLEN - k) & (KLEN - 1);
            float fr = 0.5f * (re[SWZ(k)] + re[SWZ(rk)]);
            float gr = 0.5f * (im[SWZ(k)] + im[SWZ(rk)]);
            out[obase0 + k] = fr;
            out[obase1 + k] = gr;
        }
    }
}

extern "C" void kernel_launch(void* const* d_in, const int* in_sizes, int n_in,
                              void* d_out, int out_size, void* d_ws, size_t ws_size,
                              hipStream_t stream) {
    const float* x = nullptr;
    const float* dlnf = nullptr;
    for (int i = 0; i < n_in; ++i) {
        if (in_sizes[i] == NB * NSAMP)      x = (const float*)d_in[i];
        else if (in_sizes[i] == NC)         dlnf = (const float*)d_in[i];
    }
    if (!x)    x    = (const float*)d_in[0];
    if (!dlnf) dlnf = (const float*)d_in[1];
    float* out = (float*)d_out;

    char* ws = (char*)d_ws;
    float4* map    = (float4*)ws;
    float*  g_hann = (float*)(ws + WS_HANN);

    warpmap_kernel<<<NC, 256, 0, stream>>>(dlnf, map, g_hann);

    const int nblocks = NB * NW * 2;  // 4088 blocks, 4 waves each, 1 chirp-pair per wave
    dechirp_fftw_kernel<<<nblocks, 256, 0, stream>>>(x, map, g_hann, out);
}